// Round 3
// baseline (192.776 us; speedup 1.0000x reference)
//
#include <hip/hip_runtime.h>
#include <math.h>

// DigitCaps routing, single fused kernel, one block per batch element,
// 1024 threads (16 waves = 4 waves/SIMD) for latency hiding.
// R1 (256 thr) was latency-bound: VALUBusy 12.5%, 1 wave/SIMD.
// R2 (6 kernels) paid launch gaps + the harness's fixed 42us d_ws poison.
//
// Algebra (u_hat never materialized):
//   t0[c,o,q]   = 0.1 * sum_hw u[c,hw,q]          (iter-1 uniform softmax)
//   v           = squash( s[o,p] = sum_{c,q} Wm[c,o,p,q] * t[c,o,q] )
//   logits[n,o] = u . wv,  wv[c,o,q] = sum_p Wm[c,o,p,q] * vacc[o,p],
//                 vacc = v1 (+ v2)   (b_ij accumulation is linear in v)
//   t[c,o,q]    = sum_hw softmax_o(logits) * u

#define CC 32
#define HWN 144
#define QQ 8
#define OO 10
#define PP 16
#define EE 80    // OO*QQ
#define NT 1024

__device__ __forceinline__ float compute_v(const float* __restrict__ Wm,
                                           const float* t_s, int tid) {
    // valid for tid < 160 only; returns squashed v element (o = tid>>4, p = tid&15)
    const int o = tid >> 4, p = tid & 15;
    float s = 0.f;
#pragma unroll 8
    for (int cc = 0; cc < CC; ++cc) {
        const float4* w4 = (const float4*)(Wm + (((cc * OO + o) * PP + p) * QQ));
        const float4* t4 = (const float4*)(t_s + cc * EE + o * QQ);
        float4 w0 = w4[0], w1 = w4[1];
        float4 t0 = t4[0], t1 = t4[1];
        s += w0.x * t0.x + w0.y * t0.y + w0.z * t0.z + w0.w * t0.w
           + w1.x * t1.x + w1.y * t1.y + w1.z * t1.z + w1.w * t1.w;
    }
    float sn = s * s;
#pragma unroll
    for (int m = 1; m <= 8; m <<= 1) sn += __shfl_xor(sn, m);   // sum over p (16-group)
    return s * (sqrtf(sn) / (1.f + sn));
}

__global__ __launch_bounds__(NT)
void digitcaps_fused(const float* __restrict__ x, const float* __restrict__ Wm,
                     float* __restrict__ out) {
    const int b    = blockIdx.x;
    const int tid  = threadIdx.x;
    const int c    = tid >> 5;    // 0..31
    const int slot = tid & 31;    // 0..31 (within a 32-lane wave half)

    __shared__ float usum_s[CC * QQ];       // 1 KB
    __shared__ float t_s[CC * EE];          // 10 KB
    __shared__ float wv_s[CC * EE];         // 10 KB
    __shared__ float vacc_s[OO * PP];       // 640 B
    __shared__ float t_part[CC][8][EE];     // 80 KB

    const float* xc = x + ((size_t)(b * CC + c)) * (HWN * QQ);

    // ---- Phase A: usum[c][q] = sum_hw x ----
    float us[QQ];
#pragma unroll
    for (int q = 0; q < QQ; ++q) us[q] = 0.f;
#pragma unroll
    for (int i = 0; i < 4; ++i) {
        const float4* p4 = (const float4*)(xc + (slot + (i << 5)) * QQ);
        float4 a = p4[0], d = p4[1];
        us[0] += a.x; us[1] += a.y; us[2] += a.z; us[3] += a.w;
        us[4] += d.x; us[5] += d.y; us[6] += d.z; us[7] += d.w;
    }
    if (slot < 16) {
        const float4* p4 = (const float4*)(xc + (128 + slot) * QQ);
        float4 a = p4[0], d = p4[1];
        us[0] += a.x; us[1] += a.y; us[2] += a.z; us[3] += a.w;
        us[4] += d.x; us[5] += d.y; us[6] += d.z; us[7] += d.w;
    }
#pragma unroll
    for (int m = 1; m <= 16; m <<= 1) {
#pragma unroll
        for (int q = 0; q < QQ; ++q) us[q] += __shfl_xor(us[q], m);
    }
    if (slot == 0) {
        float4* dst = (float4*)&usum_s[c * QQ];
        dst[0] = make_float4(us[0], us[1], us[2], us[3]);
        dst[1] = make_float4(us[4], us[5], us[6], us[7]);
    }
    __syncthreads();

    // t0 = 0.1 * usum (broadcast over o)
    for (int k = tid; k < CC * EE; k += NT)
        t_s[k] = 0.1f * usum_s[(k / EE) * QQ + (k & 7)];
    __syncthreads();

    // v1
    if (tid < OO * PP) vacc_s[tid] = compute_v(Wm, t_s, tid);
    __syncthreads();

    for (int iter = 0; iter < 2; ++iter) {
        // ---- C1: wv[c,o,q] = sum_p Wm[c,o,p,q] * vacc[o,p] ----
        for (int k = tid; k < CC * EE; k += NT) {
            const int cc = k / EE, rem = k - cc * EE;
            const int o = rem >> 3, q = rem & 7;
            const float* wp = Wm + ((size_t)(cc * OO + o) * PP) * QQ + q;
            float acc = 0.f;
#pragma unroll
            for (int p = 0; p < PP; ++p) acc += wp[p * QQ] * vacc_s[o * PP + p];
            wv_s[k] = acc;
        }
        __syncthreads();

        // ---- C2: per (c,slot): logits, softmax over o, tl += c_ij*u ----
        float wv[EE];
#pragma unroll
        for (int e4 = 0; e4 < EE / 4; ++e4) {
            float4 t = ((const float4*)(wv_s + c * EE))[e4];
            wv[4*e4+0] = t.x; wv[4*e4+1] = t.y; wv[4*e4+2] = t.z; wv[4*e4+3] = t.w;
        }
        float tl[EE];
#pragma unroll
        for (int e = 0; e < EE; ++e) tl[e] = 0.f;

        auto process = [&](int hw) {
            const float4* p4 = (const float4*)(xc + hw * QQ);
            float4 a = p4[0], d = p4[1];
            float u[QQ] = {a.x, a.y, a.z, a.w, d.x, d.y, d.z, d.w};
            float lg[OO];
            float mx = -1e30f;
#pragma unroll
            for (int o = 0; o < OO; ++o) {
                float s = 0.f;
#pragma unroll
                for (int q = 0; q < QQ; ++q) s += u[q] * wv[o * QQ + q];
                lg[o] = s;
                mx = fmaxf(mx, s);
            }
            float ssum = 0.f;
#pragma unroll
            for (int o = 0; o < OO; ++o) { lg[o] = __expf(lg[o] - mx); ssum += lg[o]; }
            const float inv = 1.f / ssum;
#pragma unroll
            for (int o = 0; o < OO; ++o) {
                const float cij = lg[o] * inv;
#pragma unroll
                for (int q = 0; q < QQ; ++q) tl[o * QQ + q] += cij * u[q];
            }
        };
#pragma unroll
        for (int i = 0; i < 4; ++i) process(slot + (i << 5));
        if (slot < 16) process(128 + slot);

        // reduce over slot groups of 4 (xor 1,2), spill 8 partials per c to LDS
#pragma unroll
        for (int m = 1; m <= 2; m <<= 1) {
#pragma unroll
            for (int e = 0; e < EE; ++e) tl[e] += __shfl_xor(tl[e], m);
        }
        if ((slot & 3) == 0) {
            float4* dst = (float4*)&t_part[c][slot >> 2][0];
#pragma unroll
            for (int e4 = 0; e4 < EE / 4; ++e4)
                dst[e4] = make_float4(tl[4*e4], tl[4*e4+1], tl[4*e4+2], tl[4*e4+3]);
        }
        __syncthreads();

        // stage 2: t[c,e] = sum_j t_part[c][j][e]
        for (int k = tid; k < CC * EE; k += NT) {
            const int cc = k / EE, e = k - cc * EE;
            float s = 0.f;
#pragma unroll
            for (int j = 0; j < 8; ++j) s += t_part[cc][j][e];
            t_s[k] = s;
        }
        __syncthreads();

        // ---- v = squash(Wm . t) ----
        if (tid < OO * PP) {
            float v = compute_v(Wm, t_s, tid);
            if (iter == 1) out[(size_t)b * (OO * PP) + tid] = v;
            else           vacc_s[tid] += v;
        }
        __syncthreads();
    }
}

extern "C" void kernel_launch(void* const* d_in, const int* in_sizes, int n_in,
                              void* d_out, int out_size, void* d_ws, size_t ws_size,
                              hipStream_t stream) {
    const float* x  = (const float*)d_in[0];   // [128,32,12,12,8]
    const float* Wm = (const float*)d_in[1];   // [32,10,16,8]
    float* out = (float*)d_out;                // [128,10,16]
    digitcaps_fused<<<128, NT, 0, stream>>>(x, Wm, out);
}